// Round 1
// baseline (505.719 us; speedup 1.0000x reference)
//
#include <hip/hip_runtime.h>
#include <hip/hip_bf16.h>
#include <stdint.h>

typedef unsigned short u16;
typedef __bf16 bf16x8 __attribute__((ext_vector_type(8)));
typedef float  f32x4  __attribute__((ext_vector_type(4)));

// problem dims
constexpr int NB = 64;           // batch
constexpr int NC = 256;          // cards
constexpr int NW = 256;          // words
constexpr int NE = 2048;         // E = GEMM K
constexpr int ND = 2048;         // D = GEMM N
constexpr int MROWS = NB * NW;   // 16384

constexpr int BM = 128, BN = 128, BK = 64;

// ws layout (bytes)
constexpr size_t OFF_IDX = 0;                       // 64 * 4
constexpr size_t OFF_LN  = 256;                     // 64 * 4
constexpr size_t OFF_DOT = 512;                     // 16384 * 4
constexpr size_t OFF_SSQ = 66048;                   // 16384 * 4
constexpr size_t OFF_LDR = 131584;                  // 64*2048*4
constexpr size_t OFF_A0  = 655872;                  // 128*2048*2 (bf16)
constexpr size_t OFF_WI  = 1180160;                 // 2048*2048*2
constexpr size_t OFF_WW  = OFF_WI + 8388608;        // 2048*2048*2
constexpr size_t OFF_XT  = OFF_WI + 16777216;       // 16384*2048*2
constexpr size_t NEED_FULL = OFF_XT + 67108864ull;  // ~81.1 MB

__device__ __forceinline__ u16 f2bf(float f) {
    uint32_t u = __float_as_uint(f);
    u += 0x7fffu + ((u >> 16) & 1u);   // RNE
    return (u16)(u >> 16);
}

// ---------- argmax over cards per batch (first-occurrence ties) ----------
__global__ void k_argmax(const float* __restrict__ y, int* __restrict__ idx) {
    int b = blockIdx.x;
    int l = threadIdx.x;               // 64 threads = 1 wave
    float best = -3.4e38f; int bi = 0;
    for (int j = l; j < NC; j += 64) {
        float v = y[b * NC + j];
        if (v > best) { best = v; bi = j; }
    }
    for (int off = 1; off < 64; off <<= 1) {
        float ov = __shfl_xor(best, off, 64);
        int   oi = __shfl_xor(bi,  off, 64);
        if (ov > best || (ov == best && oi < bi)) { best = ov; bi = oi; }
    }
    if (l == 0) idx[b] = bi;
}

// ---------- gather leader card rows -> bf16 A0[128][2048] (rows>=64 zero) ----------
__global__ void k_gather(const float* __restrict__ ximg, const int* __restrict__ idx,
                         u16* __restrict__ A0) {
    int r = blockIdx.x;                // 0..127
    u16* dst = A0 + (size_t)r * NE;
    if (r < NB) {
        const float* src = ximg + ((size_t)r * NC + idx[r]) * NE;
        for (int e = threadIdx.x; e < NE; e += blockDim.x) dst[e] = f2bf(src[e]);
    } else {
        for (int e = threadIdx.x; e < NE; e += blockDim.x) dst[e] = 0;
    }
}

// ---------- fp32 -> bf16 bulk convert ----------
__global__ void k_convert(const float* __restrict__ src, u16* __restrict__ dst, int n4) {
    int stride = gridDim.x * blockDim.x;
    for (int i = blockIdx.x * blockDim.x + threadIdx.x; i < n4; i += stride) {
        float4 v = ((const float4*)src)[i];
        ushort4 o = { f2bf(v.x), f2bf(v.y), f2bf(v.z), f2bf(v.w) };
        ((ushort4*)dst)[i] = o;
    }
}

// ---------- GEMM core: C[m][n] = sum_k A[m][k] * Bmat[n][k]  (+bias epilogue) ----------
// MODE 0: leader GEMM (M=64): store leader fp32, atomic lnorm2
// MODE 1: words GEMM (M=16384): fused dot-with-leader + sumsq, atomic partials
// ABF/BBF: source already bf16 (use global_load_lds) vs fp32 (fused convert)
template<int MODE, bool ABF, bool BBF>
__global__ __launch_bounds__(256) void k_gemm(
    const void* __restrict__ Av, const void* __restrict__ Bv,
    const float* __restrict__ bias, float* __restrict__ leader,
    float* __restrict__ red0, float* __restrict__ red1)
{
    __shared__ __align__(16) u16 sA[BM * BK];
    __shared__ __align__(16) u16 sB[BN * BK];

    const int t  = threadIdx.x;
    const int l  = t & 63;
    const int wv = t >> 6;
    const int wm = wv >> 1, wn = wv & 1;   // 2x2 wave grid, 64x64 per wave

    int mt, nt;
    if (MODE == 0) { mt = 0; nt = blockIdx.x; }
    else           { mt = blockIdx.x >> 4; nt = blockIdx.x & 15; }
    const int m0 = mt * BM, n0 = nt * BN;

    f32x4 acc[4][4];
    #pragma unroll
    for (int i = 0; i < 4; ++i)
        #pragma unroll
        for (int j = 0; j < 4; ++j) acc[i][j] = (f32x4){0.f, 0.f, 0.f, 0.f};

    const int lr = l >> 3;   // row within 8-row staging group
    const int lp = l & 7;    // 16B-chunk position within row

    for (int k0 = 0; k0 < NE; k0 += BK) {
        __syncthreads();
        // ---- stage A tile (BM x BK), XOR-swizzled: pos p of row r holds chunk p^(r&7)
        #pragma unroll
        for (int i = 0; i < 4; ++i) {
            int r = wv * 32 + i * 8 + lr;
            int g = lp ^ (r & 7);
            if (ABF) {
                const u16* src = (const u16*)Av + (size_t)(m0 + r) * NE + k0 + g * 8;
                __builtin_amdgcn_global_load_lds(
                    (const __attribute__((address_space(1))) void*)src,
                    (__attribute__((address_space(3))) void*)&sA[(wv * 32 + i * 8) * BK],
                    16, 0, 0);
            } else {
                const float* src = (const float*)Av + (size_t)(m0 + r) * NE + k0 + g * 8;
                float4 v0 = *(const float4*)src;
                float4 v1 = *(const float4*)(src + 4);
                uint4 ov;
                ov.x = (uint32_t)f2bf(v0.x) | ((uint32_t)f2bf(v0.y) << 16);
                ov.y = (uint32_t)f2bf(v0.z) | ((uint32_t)f2bf(v0.w) << 16);
                ov.z = (uint32_t)f2bf(v1.x) | ((uint32_t)f2bf(v1.y) << 16);
                ov.w = (uint32_t)f2bf(v1.z) | ((uint32_t)f2bf(v1.w) << 16);
                *(uint4*)&sA[r * BK + lp * 8] = ov;
            }
        }
        // ---- stage B tile (BN x BK) from Bmat rows (n index)
        #pragma unroll
        for (int i = 0; i < 4; ++i) {
            int r = wv * 32 + i * 8 + lr;
            int g = lp ^ (r & 7);
            if (BBF) {
                const u16* src = (const u16*)Bv + (size_t)(n0 + r) * NE + k0 + g * 8;
                __builtin_amdgcn_global_load_lds(
                    (const __attribute__((address_space(1))) void*)src,
                    (__attribute__((address_space(3))) void*)&sB[(wv * 32 + i * 8) * BK],
                    16, 0, 0);
            } else {
                const float* src = (const float*)Bv + (size_t)(n0 + r) * NE + k0 + g * 8;
                float4 v0 = *(const float4*)src;
                float4 v1 = *(const float4*)(src + 4);
                uint4 ov;
                ov.x = (uint32_t)f2bf(v0.x) | ((uint32_t)f2bf(v0.y) << 16);
                ov.y = (uint32_t)f2bf(v0.z) | ((uint32_t)f2bf(v0.w) << 16);
                ov.z = (uint32_t)f2bf(v1.x) | ((uint32_t)f2bf(v1.y) << 16);
                ov.w = (uint32_t)f2bf(v1.z) | ((uint32_t)f2bf(v1.w) << 16);
                *(uint4*)&sB[r * BK + lp * 8] = ov;
            }
        }
        __syncthreads();

        // ---- MFMA: 2 k-steps of 32, 4x4 fragments per wave
        #pragma unroll
        for (int kk = 0; kk < 2; ++kk) {
            bf16x8 af[4], bfr[4];
            #pragma unroll
            for (int mi = 0; mi < 4; ++mi) {
                int ra = wm * 64 + mi * 16 + (l & 15);
                int g  = kk * 4 + (l >> 4);
                int p  = g ^ (ra & 7);
                af[mi] = *(const bf16x8*)&sA[ra * BK + p * 8];
            }
            #pragma unroll
            for (int nj = 0; nj < 4; ++nj) {
                int rb = wn * 64 + nj * 16 + (l & 15);
                int g  = kk * 4 + (l >> 4);
                int p  = g ^ (rb & 7);
                bfr[nj] = *(const bf16x8*)&sB[rb * BK + p * 8];
            }
            #pragma unroll
            for (int mi = 0; mi < 4; ++mi)
                #pragma unroll
                for (int nj = 0; nj < 4; ++nj)
                    acc[mi][nj] = __builtin_amdgcn_mfma_f32_16x16x32_bf16(
                        af[mi], bfr[nj], acc[mi][nj], 0, 0, 0);
        }
    }

    // ---- epilogue ----
    const int quad = l >> 4, lc = l & 15;
    if (MODE == 0) {
        #pragma unroll
        for (int mi = 0; mi < 4; ++mi) {
            #pragma unroll
            for (int r = 0; r < 4; ++r) {
                int m = m0 + wm * 64 + mi * 16 + quad * 4 + r;
                if (m < NB) {
                    float ps = 0.f;
                    #pragma unroll
                    for (int nj = 0; nj < 4; ++nj) {
                        int n = n0 + wn * 64 + nj * 16 + lc;
                        float v = acc[mi][nj][r] + bias[n];
                        leader[(size_t)m * ND + n] = v;
                        ps += v * v;
                    }
                    for (int off = 1; off <= 8; off <<= 1) ps += __shfl_xor(ps, off, 64);
                    if (lc == 0) atomicAdd(&red0[m], ps);
                }
            }
        }
    } else {
        const int bidx = m0 >> 8;   // 256 rows per batch, BM=128 -> single batch/block
        float bia[4], ldr[4];
        #pragma unroll
        for (int nj = 0; nj < 4; ++nj) {
            int n = n0 + wn * 64 + nj * 16 + lc;
            bia[nj] = bias[n];
            ldr[nj] = leader[(size_t)bidx * ND + n];
        }
        #pragma unroll
        for (int mi = 0; mi < 4; ++mi) {
            #pragma unroll
            for (int r = 0; r < 4; ++r) {
                int m = m0 + wm * 64 + mi * 16 + quad * 4 + r;
                float pd = 0.f, ps = 0.f;
                #pragma unroll
                for (int nj = 0; nj < 4; ++nj) {
                    float v = acc[mi][nj][r] + bia[nj];
                    pd += ldr[nj] * v;
                    ps += v * v;
                }
                for (int off = 1; off <= 8; off <<= 1) {
                    pd += __shfl_xor(pd, off, 64);
                    ps += __shfl_xor(ps, off, 64);
                }
                if (lc == 0) { atomicAdd(&red0[m], pd); atomicAdd(&red1[m], ps); }
            }
        }
    }
}

// ---------- logits + softmax ----------
__global__ void k_final(const float* __restrict__ dotv, const float* __restrict__ ssq,
                        const float* __restrict__ ln2, float* __restrict__ out) {
    int b = blockIdx.x, w = threadIdx.x;   // 256 threads
    __shared__ float redm[4], reds[4];
    float dt = dotv[b * NW + w];
    float dn = sqrtf(ln2[b]) * sqrtf(ssq[b * NW + w]);
    float lg = dt / fmaxf(dn, 1e-8f);
    float mx = lg;
    for (int off = 1; off < 64; off <<= 1) mx = fmaxf(mx, __shfl_xor(mx, off, 64));
    int wvi = w >> 6;
    if ((w & 63) == 0) redm[wvi] = mx;
    __syncthreads();
    mx = fmaxf(fmaxf(redm[0], redm[1]), fmaxf(redm[2], redm[3]));
    float e = __expf(lg - mx);
    float s = e;
    for (int off = 1; off < 64; off <<= 1) s += __shfl_xor(s, off, 64);
    if ((w & 63) == 0) reds[wvi] = s;
    __syncthreads();
    s = reds[0] + reds[1] + reds[2] + reds[3];
    out[b * NW + w] = e / s;
}

extern "C" void kernel_launch(void* const* d_in, const int* in_sizes, int n_in,
                              void* d_out, int out_size, void* d_ws, size_t ws_size,
                              hipStream_t stream) {
    const float* ximg = (const float*)d_in[0];
    const float* xtxt = (const float*)d_in[1];
    const float* y    = (const float*)d_in[2];
    const float* Wimg = (const float*)d_in[3];
    const float* bimg = (const float*)d_in[4];
    const float* Wwrd = (const float*)d_in[5];
    const float* bwrd = (const float*)d_in[6];
    float* out = (float*)d_out;

    char* ws = (char*)d_ws;
    int*   idx  = (int*)(ws + OFF_IDX);
    float* ln2  = (float*)(ws + OFF_LN);
    float* dotb = (float*)(ws + OFF_DOT);
    float* ssq  = (float*)(ws + OFF_SSQ);
    float* ldr  = (float*)(ws + OFF_LDR);
    u16*   A0   = (u16*)(ws + OFF_A0);
    u16*   WIb  = (u16*)(ws + OFF_WI);
    u16*   WWb  = (u16*)(ws + OFF_WW);
    u16*   XTb  = (u16*)(ws + OFF_XT);

    const bool preconv = ws_size >= NEED_FULL;

    // zero atomic accumulators: ln2 + dot + ssq (contiguous)
    hipMemsetAsync(ws + OFF_LN, 0, OFF_LDR - OFF_LN, stream);

    k_argmax<<<NB, 64, 0, stream>>>(y, idx);
    k_gather<<<BM, 256, 0, stream>>>(ximg, idx, A0);

    if (preconv) {
        k_convert<<<2048, 256, 0, stream>>>(Wimg, WIb, ND * NE / 4);
        k_convert<<<2048, 256, 0, stream>>>(Wwrd, WWb, ND * NE / 4);
        k_convert<<<4096, 256, 0, stream>>>(xtxt, XTb, MROWS * NE / 4);
        k_gemm<0, true, true><<<ND / BN, 256, 0, stream>>>(A0, WIb, bimg, ldr, ln2, nullptr);
        k_gemm<1, true, true><<<(MROWS / BM) * (ND / BN), 256, 0, stream>>>(XTb, WWb, bwrd, ldr, dotb, ssq);
    } else {
        k_gemm<0, true, false><<<ND / BN, 256, 0, stream>>>(A0, Wimg, bimg, ldr, ln2, nullptr);
        k_gemm<1, false, false><<<(MROWS / BM) * (ND / BN), 256, 0, stream>>>(xtxt, Wwrd, bwrd, ldr, dotb, ssq);
    }
    k_final<<<NB, 256, 0, stream>>>(dotb, ssq, ln2, out);
}

// Round 2
// 485.537 us; speedup vs baseline: 1.0416x; 1.0416x over previous
//
#include <hip/hip_runtime.h>
#include <hip/hip_bf16.h>
#include <stdint.h>

typedef unsigned short u16;
typedef __bf16 bf16x8 __attribute__((ext_vector_type(8)));
typedef float  f32x4  __attribute__((ext_vector_type(4)));

// problem dims
constexpr int NB = 64;           // batch
constexpr int NC = 256;          // cards
constexpr int NW = 256;          // words
constexpr int NE = 2048;         // E = GEMM K
constexpr int ND = 2048;         // D = GEMM N
constexpr int MROWS = NB * NW;   // 16384

constexpr int BM = 128, BN = 128, BK = 64;
constexpr int KSPLIT = 8;        // split-K factor for leader GEMM
constexpr int KSLICE = NE / KSPLIT;  // 256

// ws layout (bytes)
constexpr size_t OFF_IDX  = 0;                        // 64 * 4
constexpr size_t OFF_LN   = 256;                      // 64 * 4
constexpr size_t OFF_DOT  = 512;                      // 16384 * 4
constexpr size_t OFF_SSQ  = 66048;                    // 16384 * 4
constexpr size_t OFF_LDR  = 131584;                   // 64*2048*4          -> 655872
constexpr size_t OFF_A0   = 655872;                   // 128*2048*2 bf16    -> 1180160
constexpr size_t OFF_PART = 1180160;                  // 8*64*2048*4        -> 5374464
constexpr size_t OFF_WW   = 5374464;                  // 2048*2048*2        -> 13763072
constexpr size_t OFF_XT   = 13763072;                 // 16384*2048*2       -> 80871936
constexpr size_t NEED_FULL = OFF_XT + 67108864ull;    // ~80.9 MB

__device__ __forceinline__ u16 f2bf(float f) {
    uint32_t u = __float_as_uint(f);
    u += 0x7fffu + ((u >> 16) & 1u);   // RNE
    return (u16)(u >> 16);
}

// ---------- argmax over cards per batch (first-occurrence ties) ----------
__global__ void k_argmax(const float* __restrict__ y, int* __restrict__ idx) {
    int b = blockIdx.x;
    int l = threadIdx.x;               // 64 threads = 1 wave
    float best = -3.4e38f; int bi = 0;
    for (int j = l; j < NC; j += 64) {
        float v = y[b * NC + j];
        if (v > best) { best = v; bi = j; }
    }
    for (int off = 1; off < 64; off <<= 1) {
        float ov = __shfl_xor(best, off, 64);
        int   oi = __shfl_xor(bi,  off, 64);
        if (ov > best || (ov == best && oi < bi)) { best = ov; bi = oi; }
    }
    if (l == 0) idx[b] = bi;
}

// ---------- gather leader card rows -> bf16 A0[128][2048] (rows>=64 zero) ----------
__global__ void k_gather(const float* __restrict__ ximg, const int* __restrict__ idx,
                         u16* __restrict__ A0) {
    int r = blockIdx.x;                // 0..127
    u16* dst = A0 + (size_t)r * NE;
    if (r < NB) {
        const float* src = ximg + ((size_t)r * NC + idx[r]) * NE;
        for (int e = threadIdx.x; e < NE; e += blockDim.x) dst[e] = f2bf(src[e]);
    } else {
        for (int e = threadIdx.x; e < NE; e += blockDim.x) dst[e] = 0;
    }
}

// ---------- fp32 -> bf16 bulk convert ----------
__global__ void k_convert(const float* __restrict__ src, u16* __restrict__ dst, int n4) {
    int stride = gridDim.x * blockDim.x;
    for (int i = blockIdx.x * blockDim.x + threadIdx.x; i < n4; i += stride) {
        float4 v = ((const float4*)src)[i];
        ushort4 o = { f2bf(v.x), f2bf(v.y), f2bf(v.z), f2bf(v.w) };
        ((ushort4*)dst)[i] = o;
    }
}

// ---------- split-K leader GEMM: part[ks][m][n] = sum_{k in slice} A0[m][k]*Wimg[n][k]
// A0 bf16 (global_load_lds), Wimg fp32 (fused convert). 16 nt x 8 ks = 128 blocks.
__global__ __launch_bounds__(256) void k_gemm0(
    const u16* __restrict__ A0, const float* __restrict__ Wimg,
    float* __restrict__ part)
{
    __shared__ __align__(16) u16 sA[BM * BK];
    __shared__ __align__(16) u16 sB[BN * BK];

    const int t  = threadIdx.x;
    const int l  = t & 63;
    const int wv = t >> 6;
    const int wm = wv >> 1, wn = wv & 1;

    const int nt = blockIdx.x >> 3, ks = blockIdx.x & 7;
    const int n0 = nt * BN;
    const int kbase = ks * KSLICE;

    f32x4 acc[4][4];
    #pragma unroll
    for (int i = 0; i < 4; ++i)
        #pragma unroll
        for (int j = 0; j < 4; ++j) acc[i][j] = (f32x4){0.f, 0.f, 0.f, 0.f};

    const int lr = l >> 3, lp = l & 7;

    for (int k0 = kbase; k0 < kbase + KSLICE; k0 += BK) {
        __syncthreads();
        #pragma unroll
        for (int i = 0; i < 4; ++i) {
            int r = wv * 32 + i * 8 + lr;
            int g = lp ^ (r & 7);
            const u16* src = A0 + (size_t)r * NE + k0 + g * 8;
            __builtin_amdgcn_global_load_lds(
                (const __attribute__((address_space(1))) void*)src,
                (__attribute__((address_space(3))) void*)&sA[(wv * 32 + i * 8) * BK],
                16, 0, 0);
        }
        #pragma unroll
        for (int i = 0; i < 4; ++i) {
            int r = wv * 32 + i * 8 + lr;
            int g = lp ^ (r & 7);
            const float* src = Wimg + (size_t)(n0 + r) * NE + k0 + g * 8;
            float4 v0 = *(const float4*)src;
            float4 v1 = *(const float4*)(src + 4);
            uint4 ov;
            ov.x = (uint32_t)f2bf(v0.x) | ((uint32_t)f2bf(v0.y) << 16);
            ov.y = (uint32_t)f2bf(v0.z) | ((uint32_t)f2bf(v0.w) << 16);
            ov.z = (uint32_t)f2bf(v1.x) | ((uint32_t)f2bf(v1.y) << 16);
            ov.w = (uint32_t)f2bf(v1.z) | ((uint32_t)f2bf(v1.w) << 16);
            *(uint4*)&sB[r * BK + lp * 8] = ov;
        }
        __syncthreads();

        #pragma unroll
        for (int kk = 0; kk < 2; ++kk) {
            bf16x8 af[4], bfr[4];
            #pragma unroll
            for (int mi = 0; mi < 4; ++mi) {
                int ra = wm * 64 + mi * 16 + (l & 15);
                int g  = kk * 4 + (l >> 4);
                int p  = g ^ (ra & 7);
                af[mi] = *(const bf16x8*)&sA[ra * BK + p * 8];
            }
            #pragma unroll
            for (int nj = 0; nj < 4; ++nj) {
                int rb = wn * 64 + nj * 16 + (l & 15);
                int g  = kk * 4 + (l >> 4);
                int p  = g ^ (rb & 7);
                bfr[nj] = *(const bf16x8*)&sB[rb * BK + p * 8];
            }
            #pragma unroll
            for (int mi = 0; mi < 4; ++mi)
                #pragma unroll
                for (int nj = 0; nj < 4; ++nj)
                    acc[mi][nj] = __builtin_amdgcn_mfma_f32_16x16x32_bf16(
                        af[mi], bfr[nj], acc[mi][nj], 0, 0, 0);
        }
    }

    // store partials (rows 0..63 live in wm==0 waves)
    if (wm == 0) {
        const int quad = l >> 4, lc = l & 15;
        #pragma unroll
        for (int mi = 0; mi < 4; ++mi)
            #pragma unroll
            for (int r = 0; r < 4; ++r) {
                int m = mi * 16 + quad * 4 + r;     // 0..63
                #pragma unroll
                for (int nj = 0; nj < 4; ++nj) {
                    int n = n0 + wn * 64 + nj * 16 + lc;
                    part[((size_t)ks * NB + m) * ND + n] = acc[mi][nj][r];
                }
            }
    }
}

// ---------- reduce partials, add bias, write leader fp32 + ln2 ----------
__global__ void k_leaderfix(const float* __restrict__ part, const float* __restrict__ bias,
                            float* __restrict__ leader, float* __restrict__ ln2) {
    int b = blockIdx.x, t = threadIdx.x;   // 256 threads
    float s2 = 0.f;
    #pragma unroll
    for (int i = 0; i < 8; ++i) {
        int d = i * 256 + t;
        float s = bias[d];
        #pragma unroll
        for (int ks = 0; ks < KSPLIT; ++ks)
            s += part[((size_t)ks * NB + b) * ND + d];
        leader[(size_t)b * ND + d] = s;
        s2 += s * s;
    }
    for (int off = 1; off < 64; off <<= 1) s2 += __shfl_xor(s2, off, 64);
    __shared__ float red[4];
    if ((t & 63) == 0) red[t >> 6] = s2;
    __syncthreads();
    if (t == 0) ln2[b] = red[0] + red[1] + red[2] + red[3];
}

// ---------- big GEMM: fused dot-with-leader + sumsq epilogue ----------
// ABF/BBF: source already bf16 (global_load_lds) vs fp32 (fused convert)
template<bool ABF, bool BBF>
__global__ __launch_bounds__(256) void k_gemm1(
    const void* __restrict__ Av, const void* __restrict__ Bv,
    const float* __restrict__ bias, const float* __restrict__ leader,
    float* __restrict__ dotv, float* __restrict__ ssq)
{
    __shared__ __align__(16) u16 sA[BM * BK];
    __shared__ __align__(16) u16 sB[BN * BK];

    const int t  = threadIdx.x;
    const int l  = t & 63;
    const int wv = t >> 6;
    const int wm = wv >> 1, wn = wv & 1;

    // XCD-aware swizzle: blocks round-robin XCDs by blockIdx % 8. Give each XCD
    // a contiguous mt range; consecutive per-XCD blocks share an A-tile (hot in
    // that XCD's L2) and sweep nt (B re-read from L3).
    const int xcd = blockIdx.x & 7;
    const int j   = blockIdx.x >> 3;          // 0..255
    const int mt  = xcd * 16 + (j >> 4);      // 0..127
    const int nt  = j & 15;                   // 0..15
    const int m0 = mt * BM, n0 = nt * BN;

    f32x4 acc[4][4];
    #pragma unroll
    for (int i = 0; i < 4; ++i)
        #pragma unroll
        for (int jj = 0; jj < 4; ++jj) acc[i][jj] = (f32x4){0.f, 0.f, 0.f, 0.f};

    const int lr = l >> 3, lp = l & 7;

    for (int k0 = 0; k0 < NE; k0 += BK) {
        __syncthreads();
        #pragma unroll
        for (int i = 0; i < 4; ++i) {
            int r = wv * 32 + i * 8 + lr;
            int g = lp ^ (r & 7);
            if (ABF) {
                const u16* src = (const u16*)Av + (size_t)(m0 + r) * NE + k0 + g * 8;
                __builtin_amdgcn_global_load_lds(
                    (const __attribute__((address_space(1))) void*)src,
                    (__attribute__((address_space(3))) void*)&sA[(wv * 32 + i * 8) * BK],
                    16, 0, 0);
            } else {
                const float* src = (const float*)Av + (size_t)(m0 + r) * NE + k0 + g * 8;
                float4 v0 = *(const float4*)src;
                float4 v1 = *(const float4*)(src + 4);
                uint4 ov;
                ov.x = (uint32_t)f2bf(v0.x) | ((uint32_t)f2bf(v0.y) << 16);
                ov.y = (uint32_t)f2bf(v0.z) | ((uint32_t)f2bf(v0.w) << 16);
                ov.z = (uint32_t)f2bf(v1.x) | ((uint32_t)f2bf(v1.y) << 16);
                ov.w = (uint32_t)f2bf(v1.z) | ((uint32_t)f2bf(v1.w) << 16);
                *(uint4*)&sA[r * BK + lp * 8] = ov;
            }
        }
        #pragma unroll
        for (int i = 0; i < 4; ++i) {
            int r = wv * 32 + i * 8 + lr;
            int g = lp ^ (r & 7);
            if (BBF) {
                const u16* src = (const u16*)Bv + (size_t)(n0 + r) * NE + k0 + g * 8;
                __builtin_amdgcn_global_load_lds(
                    (const __attribute__((address_space(1))) void*)src,
                    (__attribute__((address_space(3))) void*)&sB[(wv * 32 + i * 8) * BK],
                    16, 0, 0);
            } else {
                const float* src = (const float*)Bv + (size_t)(n0 + r) * NE + k0 + g * 8;
                float4 v0 = *(const float4*)src;
                float4 v1 = *(const float4*)(src + 4);
                uint4 ov;
                ov.x = (uint32_t)f2bf(v0.x) | ((uint32_t)f2bf(v0.y) << 16);
                ov.y = (uint32_t)f2bf(v0.z) | ((uint32_t)f2bf(v0.w) << 16);
                ov.z = (uint32_t)f2bf(v1.x) | ((uint32_t)f2bf(v1.y) << 16);
                ov.w = (uint32_t)f2bf(v1.z) | ((uint32_t)f2bf(v1.w) << 16);
                *(uint4*)&sB[r * BK + lp * 8] = ov;
            }
        }
        __syncthreads();

        #pragma unroll
        for (int kk = 0; kk < 2; ++kk) {
            bf16x8 af[4], bfr[4];
            #pragma unroll
            for (int mi = 0; mi < 4; ++mi) {
                int ra = wm * 64 + mi * 16 + (l & 15);
                int g  = kk * 4 + (l >> 4);
                int p  = g ^ (ra & 7);
                af[mi] = *(const bf16x8*)&sA[ra * BK + p * 8];
            }
            #pragma unroll
            for (int nj = 0; nj < 4; ++nj) {
                int rb = wn * 64 + nj * 16 + (l & 15);
                int g  = kk * 4 + (l >> 4);
                int p  = g ^ (rb & 7);
                bfr[nj] = *(const bf16x8*)&sB[rb * BK + p * 8];
            }
            #pragma unroll
            for (int mi = 0; mi < 4; ++mi)
                #pragma unroll
                for (int nj = 0; nj < 4; ++nj)
                    acc[mi][nj] = __builtin_amdgcn_mfma_f32_16x16x32_bf16(
                        af[mi], bfr[nj], acc[mi][nj], 0, 0, 0);
        }
    }

    // epilogue: dot with leader + sumsq, atomic partials per row
    const int quad = l >> 4, lc = l & 15;
    const int bidx = m0 >> 8;   // 256 words per batch, BM=128 -> single batch/block
    float bia[4], ldr[4];
    #pragma unroll
    for (int nj = 0; nj < 4; ++nj) {
        int n = n0 + wn * 64 + nj * 16 + lc;
        bia[nj] = bias[n];
        ldr[nj] = leader[(size_t)bidx * ND + n];
    }
    #pragma unroll
    for (int mi = 0; mi < 4; ++mi) {
        #pragma unroll
        for (int r = 0; r < 4; ++r) {
            int m = m0 + wm * 64 + mi * 16 + quad * 4 + r;
            float pd = 0.f, ps = 0.f;
            #pragma unroll
            for (int nj = 0; nj < 4; ++nj) {
                float v = acc[mi][nj][r] + bia[nj];
                pd += ldr[nj] * v;
                ps += v * v;
            }
            for (int off = 1; off <= 8; off <<= 1) {
                pd += __shfl_xor(pd, off, 64);
                ps += __shfl_xor(ps, off, 64);
            }
            if (lc == 0) { atomicAdd(&dotv[m], pd); atomicAdd(&ssq[m], ps); }
        }
    }
}

// ---------- logits + softmax ----------
__global__ void k_final(const float* __restrict__ dotv, const float* __restrict__ ssq,
                        const float* __restrict__ ln2, float* __restrict__ out) {
    int b = blockIdx.x, w = threadIdx.x;   // 256 threads
    __shared__ float redm[4], reds[4];
    float dt = dotv[b * NW + w];
    float dn = sqrtf(ln2[b]) * sqrtf(ssq[b * NW + w]);
    float lg = dt / fmaxf(dn, 1e-8f);
    float mx = lg;
    for (int off = 1; off < 64; off <<= 1) mx = fmaxf(mx, __shfl_xor(mx, off, 64));
    int wvi = w >> 6;
    if ((w & 63) == 0) redm[wvi] = mx;
    __syncthreads();
    mx = fmaxf(fmaxf(redm[0], redm[1]), fmaxf(redm[2], redm[3]));
    float e = __expf(lg - mx);
    float s = e;
    for (int off = 1; off < 64; off <<= 1) s += __shfl_xor(s, off, 64);
    if ((w & 63) == 0) reds[wvi] = s;
    __syncthreads();
    s = reds[0] + reds[1] + reds[2] + reds[3];
    out[b * NW + w] = e / s;
}

extern "C" void kernel_launch(void* const* d_in, const int* in_sizes, int n_in,
                              void* d_out, int out_size, void* d_ws, size_t ws_size,
                              hipStream_t stream) {
    const float* ximg = (const float*)d_in[0];
    const float* xtxt = (const float*)d_in[1];
    const float* y    = (const float*)d_in[2];
    const float* Wimg = (const float*)d_in[3];
    const float* bimg = (const float*)d_in[4];
    const float* Wwrd = (const float*)d_in[5];
    const float* bwrd = (const float*)d_in[6];
    float* out = (float*)d_out;

    char* ws = (char*)d_ws;
    int*   idx  = (int*)(ws + OFF_IDX);
    float* ln2  = (float*)(ws + OFF_LN);
    float* dotb = (float*)(ws + OFF_DOT);
    float* ssq  = (float*)(ws + OFF_SSQ);
    float* ldr  = (float*)(ws + OFF_LDR);
    u16*   A0   = (u16*)(ws + OFF_A0);
    float* part = (float*)(ws + OFF_PART);
    u16*   WWb  = (u16*)(ws + OFF_WW);
    u16*   XTb  = (u16*)(ws + OFF_XT);

    const bool preconv = ws_size >= NEED_FULL;

    // zero atomic accumulators (dot + ssq contiguous)
    hipMemsetAsync(ws + OFF_DOT, 0, OFF_LDR - OFF_DOT, stream);

    k_argmax<<<NB, 64, 0, stream>>>(y, idx);
    k_gather<<<BM, 256, 0, stream>>>(ximg, idx, A0);
    k_gemm0<<<(ND / BN) * KSPLIT, 256, 0, stream>>>(A0, Wimg, part);
    k_leaderfix<<<NB, 256, 0, stream>>>(part, bimg, ldr, ln2);

    if (preconv) {
        k_convert<<<2048, 256, 0, stream>>>(Wwrd, WWb, ND * NE / 4);
        k_convert<<<4096, 256, 0, stream>>>(xtxt, XTb, MROWS * NE / 4);
        k_gemm1<true, true><<<(MROWS / BM) * (ND / BN), 256, 0, stream>>>(
            XTb, WWb, bwrd, ldr, dotb, ssq);
    } else {
        k_gemm1<false, false><<<(MROWS / BM) * (ND / BN), 256, 0, stream>>>(
            xtxt, Wwrd, bwrd, ldr, dotb, ssq);
    }
    k_final<<<NB, 256, 0, stream>>>(dotb, ssq, ln2, out);
}

// Round 4
// 463.986 us; speedup vs baseline: 1.0899x; 1.0464x over previous
//
#include <hip/hip_runtime.h>
#include <hip/hip_bf16.h>
#include <stdint.h>

typedef unsigned short u16;
typedef __bf16 bf16x8 __attribute__((ext_vector_type(8)));
typedef float  f32x4  __attribute__((ext_vector_type(4)));
typedef float  fvec4  __attribute__((ext_vector_type(4)));   // native vec for nontemporal

// problem dims
constexpr int NB = 64;           // batch
constexpr int NC = 256;          // cards
constexpr int NW = 256;          // words
constexpr int NE = 2048;         // E = GEMM K
constexpr int ND = 2048;         // D = GEMM N
constexpr int MROWS = NB * NW;   // 16384

constexpr int BM = 128, BN = 128, BK = 64;
constexpr int KSPLIT = 8;        // split-K factor for leader GEMM
constexpr int KSLICE = NE / KSPLIT;  // 256
constexpr int NSLOT = 32;        // dot/ssq partial slots = 16 nt x 2 wn

// ws layout (bytes). SHARED region is reused: gemm0 split-K partials first
// (consumed by k_leaderfix), then gemm1 dot/ssq partials (written later).
constexpr size_t OFF_LN     = 0;                        // 64 * 4
constexpr size_t OFF_LDR    = 256;                      // 64*2048*4   -> 524544
constexpr size_t OFF_A0     = 524544;                   // 128*2048*2  -> 1048832
constexpr size_t OFF_SHARED = 1048832;                  // 4 MB        -> 5243136
constexpr size_t OFF_WW     = 5243136;                  // 2048*2048*2 -> 13631744
constexpr size_t OFF_XT     = 13631744;                 // 16384*2048*2
constexpr size_t NEED_FULL  = OFF_XT + 67108864ull;     // 80740608 ≈ 77.0 MB

__device__ __forceinline__ u16 f2bf(float f) {
    uint32_t u = __float_as_uint(f);
    u += 0x7fffu + ((u >> 16) & 1u);   // RNE
    return (u16)(u >> 16);
}

// ---------- fused argmax + gather leader rows -> bf16 A0[128][2048] ----------
__global__ void k_gather(const float* __restrict__ y, const float* __restrict__ ximg,
                         u16* __restrict__ A0) {
    int r = blockIdx.x;                // 0..127
    int t = threadIdx.x;               // 256
    u16* dst = A0 + (size_t)r * NE;
    if (r >= NB) {
        for (int e = t; e < NE; e += 256) dst[e] = 0;
        return;
    }
    __shared__ float sv[4];
    __shared__ int   si[4];
    __shared__ int   sidx;
    float v = y[r * NC + t];
    int   i = t;
    for (int off = 1; off < 64; off <<= 1) {
        float ov = __shfl_xor(v, off, 64);
        int   oi = __shfl_xor(i, off, 64);
        if (ov > v || (ov == v && oi < i)) { v = ov; i = oi; }
    }
    if ((t & 63) == 0) { sv[t >> 6] = v; si[t >> 6] = i; }
    __syncthreads();
    if (t == 0) {
        float bv = sv[0]; int bi = si[0];
        for (int w = 1; w < 4; ++w)
            if (sv[w] > bv || (sv[w] == bv && si[w] < bi)) { bv = sv[w]; bi = si[w]; }
        sidx = bi;
    }
    __syncthreads();
    const float* src = ximg + ((size_t)r * NC + sidx) * NE;
    for (int e = t; e < NE; e += 256) dst[e] = f2bf(src[e]);
}

// ---------- fused fp32 -> bf16 convert of Wwrd and xtxt ----------
__global__ void k_convert2(const float* __restrict__ a, u16* __restrict__ da, int n4a,
                           const float* __restrict__ b, u16* __restrict__ db, int n4b) {
    int stride = gridDim.x * blockDim.x;
    int n4 = n4a + n4b;
    for (int i = blockIdx.x * blockDim.x + threadIdx.x; i < n4; i += stride) {
        const fvec4* sp; ushort4* dp; int j;
        if (i < n4a) { sp = (const fvec4*)a; dp = (ushort4*)da; j = i; }
        else         { sp = (const fvec4*)b; dp = (ushort4*)db; j = i - n4a; }
        fvec4 v = __builtin_nontemporal_load(&sp[j]);   // read-once stream: keep L3 for bf16
        ushort4 o = { f2bf(v.x), f2bf(v.y), f2bf(v.z), f2bf(v.w) };
        dp[j] = o;
    }
}

// ---------- split-K leader GEMM: part[ks][m][n] = sum_{k in slice} A0[m][k]*Wimg[n][k]
__global__ __launch_bounds__(256) void k_gemm0(
    const u16* __restrict__ A0, const float* __restrict__ Wimg,
    float* __restrict__ part)
{
    __shared__ __align__(16) u16 sA[BM * BK];
    __shared__ __align__(16) u16 sB[BN * BK];

    const int t  = threadIdx.x;
    const int l  = t & 63;
    const int wv = t >> 6;
    const int wm = wv >> 1, wn = wv & 1;

    const int nt = blockIdx.x >> 3, ks = blockIdx.x & 7;
    const int n0 = nt * BN;
    const int kbase = ks * KSLICE;

    f32x4 acc[4][4];
    #pragma unroll
    for (int i = 0; i < 4; ++i)
        #pragma unroll
        for (int j = 0; j < 4; ++j) acc[i][j] = (f32x4){0.f, 0.f, 0.f, 0.f};

    const int lr = l >> 3, lp = l & 7;

    for (int k0 = kbase; k0 < kbase + KSLICE; k0 += BK) {
        __syncthreads();
        #pragma unroll
        for (int i = 0; i < 4; ++i) {
            int r = wv * 32 + i * 8 + lr;
            int g = lp ^ (r & 7);
            const u16* src = A0 + (size_t)r * NE + k0 + g * 8;
            __builtin_amdgcn_global_load_lds(
                (const __attribute__((address_space(1))) void*)src,
                (__attribute__((address_space(3))) void*)&sA[(wv * 32 + i * 8) * BK],
                16, 0, 0);
        }
        #pragma unroll
        for (int i = 0; i < 4; ++i) {
            int r = wv * 32 + i * 8 + lr;
            int g = lp ^ (r & 7);
            const float* src = Wimg + (size_t)(n0 + r) * NE + k0 + g * 8;
            float4 v0 = *(const float4*)src;
            float4 v1 = *(const float4*)(src + 4);
            uint4 ov;
            ov.x = (uint32_t)f2bf(v0.x) | ((uint32_t)f2bf(v0.y) << 16);
            ov.y = (uint32_t)f2bf(v0.z) | ((uint32_t)f2bf(v0.w) << 16);
            ov.z = (uint32_t)f2bf(v1.x) | ((uint32_t)f2bf(v1.y) << 16);
            ov.w = (uint32_t)f2bf(v1.z) | ((uint32_t)f2bf(v1.w) << 16);
            *(uint4*)&sB[r * BK + lp * 8] = ov;
        }
        __syncthreads();

        #pragma unroll
        for (int kk = 0; kk < 2; ++kk) {
            bf16x8 af[4], bfr[4];
            #pragma unroll
            for (int mi = 0; mi < 4; ++mi) {
                int ra = wm * 64 + mi * 16 + (l & 15);
                int g  = kk * 4 + (l >> 4);
                int p  = g ^ (ra & 7);
                af[mi] = *(const bf16x8*)&sA[ra * BK + p * 8];
            }
            #pragma unroll
            for (int nj = 0; nj < 4; ++nj) {
                int rb = wn * 64 + nj * 16 + (l & 15);
                int g  = kk * 4 + (l >> 4);
                int p  = g ^ (rb & 7);
                bfr[nj] = *(const bf16x8*)&sB[rb * BK + p * 8];
            }
            #pragma unroll
            for (int mi = 0; mi < 4; ++mi)
                #pragma unroll
                for (int nj = 0; nj < 4; ++nj)
                    acc[mi][nj] = __builtin_amdgcn_mfma_f32_16x16x32_bf16(
                        af[mi], bfr[nj], acc[mi][nj], 0, 0, 0);
        }
    }

    if (wm == 0) {
        const int quad = l >> 4, lc = l & 15;
        #pragma unroll
        for (int mi = 0; mi < 4; ++mi)
            #pragma unroll
            for (int r = 0; r < 4; ++r) {
                int m = mi * 16 + quad * 4 + r;     // 0..63
                #pragma unroll
                for (int nj = 0; nj < 4; ++nj) {
                    int n = n0 + wn * 64 + nj * 16 + lc;
                    part[((size_t)ks * NB + m) * ND + n] = acc[mi][nj][r];
                }
            }
    }
}

// ---------- reduce partials, add bias, write leader fp32 + ln2 ----------
__global__ void k_leaderfix(const float* __restrict__ part, const float* __restrict__ bias,
                            float* __restrict__ leader, float* __restrict__ ln2) {
    int b = blockIdx.x, t = threadIdx.x;   // 256 threads
    float s2 = 0.f;
    #pragma unroll
    for (int i = 0; i < 8; ++i) {
        int d = i * 256 + t;
        float s = bias[d];
        #pragma unroll
        for (int ks = 0; ks < KSPLIT; ++ks)
            s += part[((size_t)ks * NB + b) * ND + d];
        leader[(size_t)b * ND + d] = s;
        s2 += s * s;
    }
    for (int off = 1; off < 64; off <<= 1) s2 += __shfl_xor(s2, off, 64);
    __shared__ float red[4];
    if ((t & 63) == 0) red[t >> 6] = s2;
    __syncthreads();
    if (t == 0) ln2[b] = red[0] + red[1] + red[2] + red[3];
}

// ---------- big GEMM: fused dot-with-leader + sumsq, slot-partial epilogue ----------
template<bool ABF, bool BBF>
__global__ __launch_bounds__(256) void k_gemm1(
    const void* __restrict__ Av, const void* __restrict__ Bv,
    const float* __restrict__ bias, const float* __restrict__ leader,
    float* __restrict__ dotp, float* __restrict__ ssqp)
{
    __shared__ __align__(16) u16 sA[BM * BK];
    __shared__ __align__(16) u16 sB[BN * BK];

    const int t  = threadIdx.x;
    const int l  = t & 63;
    const int wv = t >> 6;
    const int wm = wv >> 1, wn = wv & 1;

    // natural mapping (round-1): consecutive blocks share mt and sweep nt;
    // per-XCD (blockIdx%8) concurrent blocks keep B-tiles hot. XCD swizzle regressed.
    const int mt = blockIdx.x >> 4;           // 0..127
    const int nt = blockIdx.x & 15;           // 0..15
    const int m0 = mt * BM, n0 = nt * BN;

    f32x4 acc[4][4];
    #pragma unroll
    for (int i = 0; i < 4; ++i)
        #pragma unroll
        for (int jj = 0; jj < 4; ++jj) acc[i][jj] = (f32x4){0.f, 0.f, 0.f, 0.f};

    const int lr = l >> 3, lp = l & 7;

    for (int k0 = 0; k0 < NE; k0 += BK) {
        __syncthreads();
        #pragma unroll
        for (int i = 0; i < 4; ++i) {
            int r = wv * 32 + i * 8 + lr;
            int g = lp ^ (r & 7);
            if (ABF) {
                const u16* src = (const u16*)Av + (size_t)(m0 + r) * NE + k0 + g * 8;
                __builtin_amdgcn_global_load_lds(
                    (const __attribute__((address_space(1))) void*)src,
                    (__attribute__((address_space(3))) void*)&sA[(wv * 32 + i * 8) * BK],
                    16, 0, 0);
            } else {
                const float* src = (const float*)Av + (size_t)(m0 + r) * NE + k0 + g * 8;
                float4 v0 = *(const float4*)src;
                float4 v1 = *(const float4*)(src + 4);
                uint4 ov;
                ov.x = (uint32_t)f2bf(v0.x) | ((uint32_t)f2bf(v0.y) << 16);
                ov.y = (uint32_t)f2bf(v0.z) | ((uint32_t)f2bf(v0.w) << 16);
                ov.z = (uint32_t)f2bf(v1.x) | ((uint32_t)f2bf(v1.y) << 16);
                ov.w = (uint32_t)f2bf(v1.z) | ((uint32_t)f2bf(v1.w) << 16);
                *(uint4*)&sA[r * BK + lp * 8] = ov;
            }
        }
        #pragma unroll
        for (int i = 0; i < 4; ++i) {
            int r = wv * 32 + i * 8 + lr;
            int g = lp ^ (r & 7);
            if (BBF) {
                const u16* src = (const u16*)Bv + (size_t)(n0 + r) * NE + k0 + g * 8;
                __builtin_amdgcn_global_load_lds(
                    (const __attribute__((address_space(1))) void*)src,
                    (__attribute__((address_space(3))) void*)&sB[(wv * 32 + i * 8) * BK],
                    16, 0, 0);
            } else {
                const float* src = (const float*)Bv + (size_t)(n0 + r) * NE + k0 + g * 8;
                float4 v0 = *(const float4*)src;
                float4 v1 = *(const float4*)(src + 4);
                uint4 ov;
                ov.x = (uint32_t)f2bf(v0.x) | ((uint32_t)f2bf(v0.y) << 16);
                ov.y = (uint32_t)f2bf(v0.z) | ((uint32_t)f2bf(v0.w) << 16);
                ov.z = (uint32_t)f2bf(v1.x) | ((uint32_t)f2bf(v1.y) << 16);
                ov.w = (uint32_t)f2bf(v1.z) | ((uint32_t)f2bf(v1.w) << 16);
                *(uint4*)&sB[r * BK + lp * 8] = ov;
            }
        }
        __syncthreads();

        #pragma unroll
        for (int kk = 0; kk < 2; ++kk) {
            bf16x8 af[4], bfr[4];
            #pragma unroll
            for (int mi = 0; mi < 4; ++mi) {
                int ra = wm * 64 + mi * 16 + (l & 15);
                int g  = kk * 4 + (l >> 4);
                int p  = g ^ (ra & 7);
                af[mi] = *(const bf16x8*)&sA[ra * BK + p * 8];
            }
            #pragma unroll
            for (int nj = 0; nj < 4; ++nj) {
                int rb = wn * 64 + nj * 16 + (l & 15);
                int g  = kk * 4 + (l >> 4);
                int p  = g ^ (rb & 7);
                bfr[nj] = *(const bf16x8*)&sB[rb * BK + p * 8];
            }
            #pragma unroll
            for (int mi = 0; mi < 4; ++mi)
                #pragma unroll
                for (int nj = 0; nj < 4; ++nj)
                    acc[mi][nj] = __builtin_amdgcn_mfma_f32_16x16x32_bf16(
                        af[mi], bfr[nj], acc[mi][nj], 0, 0, 0);
        }
    }

    // epilogue: dot with leader + sumsq -> unique partial slot (nt, wn). No atomics,
    // no zero-init needed: every slot x row written exactly once.
    const int quad = l >> 4, lc = l & 15;
    const int bidx = m0 >> 8;   // 256 words per batch, BM=128 -> single batch/block
    const int slot = nt * 2 + wn;
    float bia[4], ldr[4];
    #pragma unroll
    for (int nj = 0; nj < 4; ++nj) {
        int n = n0 + wn * 64 + nj * 16 + lc;
        bia[nj] = bias[n];
        ldr[nj] = leader[(size_t)bidx * ND + n];
    }
    #pragma unroll
    for (int mi = 0; mi < 4; ++mi) {
        #pragma unroll
        for (int r = 0; r < 4; ++r) {
            int m = m0 + wm * 64 + mi * 16 + quad * 4 + r;
            float pd = 0.f, ps = 0.f;
            #pragma unroll
            for (int nj = 0; nj < 4; ++nj) {
                float v = acc[mi][nj][r] + bia[nj];
                pd += ldr[nj] * v;
                ps += v * v;
            }
            for (int off = 1; off <= 8; off <<= 1) {
                pd += __shfl_xor(pd, off, 64);
                ps += __shfl_xor(ps, off, 64);
            }
            if (lc == 0) {
                dotp[(size_t)slot * MROWS + m] = pd;
                ssqp[(size_t)slot * MROWS + m] = ps;
            }
        }
    }
}

// ---------- reduce slot partials, logits + softmax ----------
__global__ void k_final(const float* __restrict__ dotp, const float* __restrict__ ssqp,
                        const float* __restrict__ ln2, float* __restrict__ out) {
    int b = blockIdx.x, w = threadIdx.x;   // 256 threads
    __shared__ float redm[4], reds[4];
    int m = b * NW + w;
    float dt = 0.f, sq = 0.f;
    #pragma unroll
    for (int s = 0; s < NSLOT; ++s) {
        dt += dotp[(size_t)s * MROWS + m];
        sq += ssqp[(size_t)s * MROWS + m];
    }
    float dn = sqrtf(ln2[b]) * sqrtf(sq);
    float lg = dt / fmaxf(dn, 1e-8f);
    float mx = lg;
    for (int off = 1; off < 64; off <<= 1) mx = fmaxf(mx, __shfl_xor(mx, off, 64));
    int wvi = w >> 6;
    if ((w & 63) == 0) redm[wvi] = mx;
    __syncthreads();
    mx = fmaxf(fmaxf(redm[0], redm[1]), fmaxf(redm[2], redm[3]));
    float e = __expf(lg - mx);
    float s = e;
    for (int off = 1; off < 64; off <<= 1) s += __shfl_xor(s, off, 64);
    if ((w & 63) == 0) reds[wvi] = s;
    __syncthreads();
    s = reds[0] + reds[1] + reds[2] + reds[3];
    out[b * NW + w] = e / s;
}

extern "C" void kernel_launch(void* const* d_in, const int* in_sizes, int n_in,
                              void* d_out, int out_size, void* d_ws, size_t ws_size,
                              hipStream_t stream) {
    const float* ximg = (const float*)d_in[0];
    const float* xtxt = (const float*)d_in[1];
    const float* y    = (const float*)d_in[2];
    const float* Wimg = (const float*)d_in[3];
    const float* bimg = (const float*)d_in[4];
    const float* Wwrd = (const float*)d_in[5];
    const float* bwrd = (const float*)d_in[6];
    float* out = (float*)d_out;

    char* ws = (char*)d_ws;
    float* ln2  = (float*)(ws + OFF_LN);
    float* ldr  = (float*)(ws + OFF_LDR);
    u16*   A0   = (u16*)(ws + OFF_A0);
    float* part = (float*)(ws + OFF_SHARED);                      // gemm0 split-K
    float* dotp = (float*)(ws + OFF_SHARED);                      // aliases part (later)
    float* ssqp = (float*)(ws + OFF_SHARED + (size_t)NSLOT * MROWS * 4);
    u16*   WWb  = (u16*)(ws + OFF_WW);
    u16*   XTb  = (u16*)(ws + OFF_XT);

    const bool preconv = ws_size >= NEED_FULL;

    k_gather<<<BM, 256, 0, stream>>>(y, ximg, A0);
    k_gemm0<<<(ND / BN) * KSPLIT, 256, 0, stream>>>(A0, Wimg, part);
    k_leaderfix<<<NB, 256, 0, stream>>>(part, bimg, ldr, ln2);

    if (preconv) {
        k_convert2<<<4096, 256, 0, stream>>>(Wwrd, WWb, ND * NE / 4,
                                             xtxt, XTb, MROWS * NE / 4);
        k_gemm1<true, true><<<(MROWS / BM) * (ND / BN), 256, 0, stream>>>(
            XTb, WWb, bwrd, ldr, dotp, ssqp);
    } else {
        k_gemm1<false, false><<<(MROWS / BM) * (ND / BN), 256, 0, stream>>>(
            xtxt, Wwrd, bwrd, ldr, dotp, ssqp);
    }
    k_final<<<NB, 256, 0, stream>>>(dotp, ssqp, ln2, out);
}

// Round 5
// 456.507 us; speedup vs baseline: 1.1078x; 1.0164x over previous
//
#include <hip/hip_runtime.h>
#include <hip/hip_bf16.h>
#include <stdint.h>

typedef unsigned short u16;
typedef __bf16 bf16x8 __attribute__((ext_vector_type(8)));
typedef float  f32x4  __attribute__((ext_vector_type(4)));
typedef float  fvec4  __attribute__((ext_vector_type(4)));   // native vec for nontemporal

// problem dims
constexpr int NB = 64;           // batch
constexpr int NC = 256;          // cards
constexpr int NW = 256;          // words
constexpr int NE = 2048;         // E = GEMM K
constexpr int ND = 2048;         // D = GEMM N
constexpr int MROWS = NB * NW;   // 16384

constexpr int BM = 128, BN = 128, BK = 64;
constexpr int KSPLIT = 4;        // split-K factor for leader GEMM
constexpr int KSLICE = NE / KSPLIT;  // 512
constexpr int NSLOT = 16;        // dot/ssq partial slots (one per nt; wn pre-reduced)

// ws layout (bytes). part stays live through k_final (read for leader + ln2).
constexpr size_t OFF_IDX  = 0;                         // 64*4 -> 256
constexpr size_t OFF_PART = 256;                       // 4*64*2048*4 = 2097152 -> 2097408
constexpr size_t OFF_DOTP = 2097408;                   // 16*16384*4 = 1048576 -> 3145984
constexpr size_t OFF_SSQP = 3145984;                   // 1048576 -> 4194560
constexpr size_t OFF_WW   = 4194560;                   // 2048*2048*2 -> 12583168
constexpr size_t OFF_XT   = 12583168;                  // 16384*2048*2
constexpr size_t NEED_FULL = OFF_XT + 67108864ull;     // 79692032 ≈ 76.0 MiB

__device__ __forceinline__ u16 f2bf(float f) {
    uint32_t u = __float_as_uint(f);
    u += 0x7fffu + ((u >> 16) & 1u);   // RNE
    return (u16)(u >> 16);
}

// ---------- fused: block 0 = argmax(y) -> idx; blocks 1.. = fp32->bf16 convert ----------
__global__ void k_conv_argmax(const float* __restrict__ a, u16* __restrict__ da, int n4a,
                              const float* __restrict__ b, u16* __restrict__ db, int n4b,
                              const float* __restrict__ y, int* __restrict__ idx) {
    if (blockIdx.x == 0) {
        // 256 threads, 64 rows, 4 lanes per row (lanes c scan j = c, c+4, ... ascending)
        int t = threadIdx.x;
        int row = t >> 2, c = t & 3;
        float best = -3.4e38f; int bi = 0;
        for (int k = 0; k < 64; ++k) {
            int j = c + k * 4;
            float v = y[row * NC + j];
            if (v > best) { best = v; bi = j; }
        }
        #pragma unroll
        for (int off = 1; off <= 2; off <<= 1) {   // reduce within lane-quad
            float ov = __shfl_xor(best, off, 64);
            int   oi = __shfl_xor(bi,   off, 64);
            if (ov > best || (ov == best && oi < bi)) { best = ov; bi = oi; }
        }
        if (c == 0) idx[row] = bi;
        return;
    }
    int i0 = (blockIdx.x - 1) * blockDim.x + threadIdx.x;
    int stride = (gridDim.x - 1) * blockDim.x;
    int n4 = n4a + n4b;
    for (int i = i0; i < n4; i += stride) {
        const fvec4* sp; ushort4* dp; int j;
        if (i < n4a) { sp = (const fvec4*)a; dp = (ushort4*)da; j = i; }
        else         { sp = (const fvec4*)b; dp = (ushort4*)db; j = i - n4a; }
        fvec4 v = __builtin_nontemporal_load(&sp[j]);   // read-once stream
        ushort4 o = { f2bf(v.x), f2bf(v.y), f2bf(v.z), f2bf(v.w) };
        dp[j] = o;
    }
}

// ---------- split-K leader GEMM with fused gather:
// part[ks][m][n] = sum_{k in slice} ximg[m, idx[m], k] * Wimg[n][k], m<64 (rows 64..127 pad)
__global__ __launch_bounds__(256) void k_gemm0(
    const float* __restrict__ ximg, const int* __restrict__ idx,
    const float* __restrict__ Wimg, float* __restrict__ part)
{
    __shared__ __align__(16) u16 sA[BM * BK];
    __shared__ __align__(16) u16 sB[BN * BK];
    __shared__ int s_idx[64];

    const int t  = threadIdx.x;
    const int l  = t & 63;
    const int wv = t >> 6;
    const int wm = wv >> 1, wn = wv & 1;

    const int nt = blockIdx.x >> 2, ks = blockIdx.x & 3;
    const int n0 = nt * BN;
    const int kbase = ks * KSLICE;

    if (t < 64) s_idx[t] = idx[t];

    f32x4 acc[4][4];
    #pragma unroll
    for (int i = 0; i < 4; ++i)
        #pragma unroll
        for (int j = 0; j < 4; ++j) acc[i][j] = (f32x4){0.f, 0.f, 0.f, 0.f};

    const int lr = l >> 3, lp = l & 7;

    for (int k0 = kbase; k0 < kbase + KSLICE; k0 += BK) {
        __syncthreads();   // also covers s_idx on first iteration
        // A tile: fp32 gather+convert; rows >= 64 are zero padding
        #pragma unroll
        for (int i = 0; i < 4; ++i) {
            int r = wv * 32 + i * 8 + lr;
            int g = lp ^ (r & 7);
            if (r < 64) {
                const float* src = ximg + ((size_t)r * NC + s_idx[r]) * NE + k0 + g * 8;
                float4 v0 = *(const float4*)src;
                float4 v1 = *(const float4*)(src + 4);
                uint4 ov;
                ov.x = (uint32_t)f2bf(v0.x) | ((uint32_t)f2bf(v0.y) << 16);
                ov.y = (uint32_t)f2bf(v0.z) | ((uint32_t)f2bf(v0.w) << 16);
                ov.z = (uint32_t)f2bf(v1.x) | ((uint32_t)f2bf(v1.y) << 16);
                ov.w = (uint32_t)f2bf(v1.z) | ((uint32_t)f2bf(v1.w) << 16);
                *(uint4*)&sA[r * BK + lp * 8] = ov;
            } else {
                *(uint4*)&sA[r * BK + lp * 8] = (uint4){0, 0, 0, 0};
            }
        }
        // B tile: Wimg fp32 fused convert
        #pragma unroll
        for (int i = 0; i < 4; ++i) {
            int r = wv * 32 + i * 8 + lr;
            int g = lp ^ (r & 7);
            const float* src = Wimg + (size_t)(n0 + r) * NE + kbase + (k0 - kbase) + g * 8;
            src = Wimg + (size_t)(n0 + r) * NE + k0 + g * 8;
            float4 v0 = *(const float4*)src;
            float4 v1 = *(const float4*)(src + 4);
            uint4 ov;
            ov.x = (uint32_t)f2bf(v0.x) | ((uint32_t)f2bf(v0.y) << 16);
            ov.y = (uint32_t)f2bf(v0.z) | ((uint32_t)f2bf(v0.w) << 16);
            ov.z = (uint32_t)f2bf(v1.x) | ((uint32_t)f2bf(v1.y) << 16);
            ov.w = (uint32_t)f2bf(v1.z) | ((uint32_t)f2bf(v1.w) << 16);
            *(uint4*)&sB[r * BK + lp * 8] = ov;
        }
        __syncthreads();

        #pragma unroll
        for (int kk = 0; kk < 2; ++kk) {
            bf16x8 af[4], bfr[4];
            #pragma unroll
            for (int mi = 0; mi < 4; ++mi) {
                int ra = wm * 64 + mi * 16 + (l & 15);
                int g  = kk * 4 + (l >> 4);
                int p  = g ^ (ra & 7);
                af[mi] = *(const bf16x8*)&sA[ra * BK + p * 8];
            }
            #pragma unroll
            for (int nj = 0; nj < 4; ++nj) {
                int rb = wn * 64 + nj * 16 + (l & 15);
                int g  = kk * 4 + (l >> 4);
                int p  = g ^ (rb & 7);
                bfr[nj] = *(const bf16x8*)&sB[rb * BK + p * 8];
            }
            #pragma unroll
            for (int mi = 0; mi < 4; ++mi)
                #pragma unroll
                for (int nj = 0; nj < 4; ++nj)
                    acc[mi][nj] = __builtin_amdgcn_mfma_f32_16x16x32_bf16(
                        af[mi], bfr[nj], acc[mi][nj], 0, 0, 0);
        }
    }

    if (wm == 0) {   // rows 0..63 live here
        const int quad = l >> 4, lc = l & 15;
        #pragma unroll
        for (int mi = 0; mi < 4; ++mi)
            #pragma unroll
            for (int r = 0; r < 4; ++r) {
                int m = mi * 16 + quad * 4 + r;     // 0..63
                #pragma unroll
                for (int nj = 0; nj < 4; ++nj) {
                    int n = n0 + wn * 64 + nj * 16 + lc;
                    part[((size_t)ks * NB + m) * ND + n] = acc[mi][nj][r];
                }
            }
    }
}

// ---------- big GEMM: fused leader-reduce + dot + sumsq, slot-partial epilogue ----------
template<bool ABF, bool BBF>
__global__ __launch_bounds__(256) void k_gemm1(
    const void* __restrict__ Av, const void* __restrict__ Bv,
    const float* __restrict__ bwrd, const float* __restrict__ bimg,
    const float* __restrict__ part,
    float* __restrict__ dotp, float* __restrict__ ssqp)
{
    __shared__ __align__(16) u16 sA[BM * BK];
    __shared__ __align__(16) u16 sB[BN * BK];

    const int t  = threadIdx.x;
    const int l  = t & 63;
    const int wv = t >> 6;
    const int wm = wv >> 1, wn = wv & 1;

    const int mt = blockIdx.x >> 4;           // 0..127
    const int nt = blockIdx.x & 15;           // 0..15
    const int m0 = mt * BM, n0 = nt * BN;

    f32x4 acc[4][4];
    #pragma unroll
    for (int i = 0; i < 4; ++i)
        #pragma unroll
        for (int jj = 0; jj < 4; ++jj) acc[i][jj] = (f32x4){0.f, 0.f, 0.f, 0.f};

    const int lr = l >> 3, lp = l & 7;

    for (int k0 = 0; k0 < NE; k0 += BK) {
        __syncthreads();
        #pragma unroll
        for (int i = 0; i < 4; ++i) {
            int r = wv * 32 + i * 8 + lr;
            int g = lp ^ (r & 7);
            if (ABF) {
                const u16* src = (const u16*)Av + (size_t)(m0 + r) * NE + k0 + g * 8;
                __builtin_amdgcn_global_load_lds(
                    (const __attribute__((address_space(1))) void*)src,
                    (__attribute__((address_space(3))) void*)&sA[(wv * 32 + i * 8) * BK],
                    16, 0, 0);
            } else {
                const float* src = (const float*)Av + (size_t)(m0 + r) * NE + k0 + g * 8;
                float4 v0 = *(const float4*)src;
                float4 v1 = *(const float4*)(src + 4);
                uint4 ov;
                ov.x = (uint32_t)f2bf(v0.x) | ((uint32_t)f2bf(v0.y) << 16);
                ov.y = (uint32_t)f2bf(v0.z) | ((uint32_t)f2bf(v0.w) << 16);
                ov.z = (uint32_t)f2bf(v1.x) | ((uint32_t)f2bf(v1.y) << 16);
                ov.w = (uint32_t)f2bf(v1.z) | ((uint32_t)f2bf(v1.w) << 16);
                *(uint4*)&sA[r * BK + lp * 8] = ov;
            }
        }
        #pragma unroll
        for (int i = 0; i < 4; ++i) {
            int r = wv * 32 + i * 8 + lr;
            int g = lp ^ (r & 7);
            if (BBF) {
                const u16* src = (const u16*)Bv + (size_t)(n0 + r) * NE + k0 + g * 8;
                __builtin_amdgcn_global_load_lds(
                    (const __attribute__((address_space(1))) void*)src,
                    (__attribute__((address_space(3))) void*)&sB[(wv * 32 + i * 8) * BK],
                    16, 0, 0);
            } else {
                const float* src = (const float*)Bv + (size_t)(n0 + r) * NE + k0 + g * 8;
                float4 v0 = *(const float4*)src;
                float4 v1 = *(const float4*)(src + 4);
                uint4 ov;
                ov.x = (uint32_t)f2bf(v0.x) | ((uint32_t)f2bf(v0.y) << 16);
                ov.y = (uint32_t)f2bf(v0.z) | ((uint32_t)f2bf(v0.w) << 16);
                ov.z = (uint32_t)f2bf(v1.x) | ((uint32_t)f2bf(v1.y) << 16);
                ov.w = (uint32_t)f2bf(v1.z) | ((uint32_t)f2bf(v1.w) << 16);
                *(uint4*)&sB[r * BK + lp * 8] = ov;
            }
        }
        __syncthreads();

        #pragma unroll
        for (int kk = 0; kk < 2; ++kk) {
            bf16x8 af[4], bfr[4];
            #pragma unroll
            for (int mi = 0; mi < 4; ++mi) {
                int ra = wm * 64 + mi * 16 + (l & 15);
                int g  = kk * 4 + (l >> 4);
                int p  = g ^ (ra & 7);
                af[mi] = *(const bf16x8*)&sA[ra * BK + p * 8];
            }
            #pragma unroll
            for (int nj = 0; nj < 4; ++nj) {
                int rb = wn * 64 + nj * 16 + (l & 15);
                int g  = kk * 4 + (l >> 4);
                int p  = g ^ (rb & 7);
                bfr[nj] = *(const bf16x8*)&sB[rb * BK + p * 8];
            }
            #pragma unroll
            for (int mi = 0; mi < 4; ++mi)
                #pragma unroll
                for (int nj = 0; nj < 4; ++nj)
                    acc[mi][nj] = __builtin_amdgcn_mfma_f32_16x16x32_bf16(
                        af[mi], bfr[nj], acc[mi][nj], 0, 0, 0);
        }
    }

    // ---- epilogue: leader from split-K partials + bias; dot + sumsq; wn-prereduce in LDS
    const int quad = l >> 4, lc = l & 15;
    const int bidx = m0 >> 8;   // 256 words per batch, BM=128 -> single batch per block
    float bia[4], ldr[4];
    #pragma unroll
    for (int nj = 0; nj < 4; ++nj) {
        int n = n0 + wn * 64 + nj * 16 + lc;
        bia[nj] = bwrd[n];
        float ld = bimg[n];
        #pragma unroll
        for (int ks = 0; ks < KSPLIT; ++ks)
            ld += part[((size_t)ks * NB + bidx) * ND + n];
        ldr[nj] = ld;
    }
    __syncthreads();                       // done with sA as tile storage
    float* sRed = (float*)sA;              // [2]: pd then ps, each [wm][wn][64]
    #pragma unroll
    for (int mi = 0; mi < 4; ++mi) {
        #pragma unroll
        for (int r = 0; r < 4; ++r) {
            float pd = 0.f, ps = 0.f;
            #pragma unroll
            for (int nj = 0; nj < 4; ++nj) {
                float v = acc[mi][nj][r] + bia[nj];
                pd += ldr[nj] * v;
                ps += v * v;
            }
            #pragma unroll
            for (int off = 1; off <= 8; off <<= 1) {
                pd += __shfl_xor(pd, off, 64);
                ps += __shfl_xor(ps, off, 64);
            }
            if (lc == 0) {
                int lm = mi * 16 + quad * 4 + r;          // 0..63 within wave's half
                sRed[(wm * 2 + wn) * 64 + lm]       = pd;
                sRed[256 + (wm * 2 + wn) * 64 + lm] = ps;
            }
        }
    }
    __syncthreads();
    if (t < 128) {
        int wmm = t >> 6, lm = t & 63;
        int m = m0 + wmm * 64 + lm;
        dotp[(size_t)nt * MROWS + m] =
            sRed[(wmm * 2 + 0) * 64 + lm] + sRed[(wmm * 2 + 1) * 64 + lm];
        ssqp[(size_t)nt * MROWS + m] =
            sRed[256 + (wmm * 2 + 0) * 64 + lm] + sRed[256 + (wmm * 2 + 1) * 64 + lm];
    }
}

// ---------- ln2 from partials, reduce slots, logits + softmax ----------
__global__ void k_final(const float* __restrict__ part, const float* __restrict__ bimg,
                        const float* __restrict__ dotp, const float* __restrict__ ssqp,
                        float* __restrict__ out) {
    int b = blockIdx.x, t = threadIdx.x;   // 256 threads
    __shared__ float rsum[4], redm[4], reds[4];
    // ln2 = || bimg + sum_ks part[ks][b][:] ||^2
    float s2 = 0.f;
    #pragma unroll
    for (int i = 0; i < 8; ++i) {
        int d = i * 256 + t;
        float ld = bimg[d];
        #pragma unroll
        for (int ks = 0; ks < KSPLIT; ++ks)
            ld += part[((size_t)ks * NB + b) * ND + d];
        s2 += ld * ld;
    }
    for (int off = 1; off < 64; off <<= 1) s2 += __shfl_xor(s2, off, 64);
    if ((t & 63) == 0) rsum[t >> 6] = s2;
    __syncthreads();
    float ln2 = rsum[0] + rsum[1] + rsum[2] + rsum[3];

    int m = b * NW + t;
    float dt = 0.f, sq = 0.f;
    #pragma unroll
    for (int s = 0; s < NSLOT; ++s) {
        dt += dotp[(size_t)s * MROWS + m];
        sq += ssqp[(size_t)s * MROWS + m];
    }
    float dn = sqrtf(ln2) * sqrtf(sq);
    float lg = dt / fmaxf(dn, 1e-8f);
    float mx = lg;
    for (int off = 1; off < 64; off <<= 1) mx = fmaxf(mx, __shfl_xor(mx, off, 64));
    int wvi = t >> 6;
    if ((t & 63) == 0) redm[wvi] = mx;
    __syncthreads();
    mx = fmaxf(fmaxf(redm[0], redm[1]), fmaxf(redm[2], redm[3]));
    float e = __expf(lg - mx);
    float s = e;
    for (int off = 1; off < 64; off <<= 1) s += __shfl_xor(s, off, 64);
    if ((t & 63) == 0) reds[wvi] = s;
    __syncthreads();
    s = reds[0] + reds[1] + reds[2] + reds[3];
    out[m] = e / s;
}

extern "C" void kernel_launch(void* const* d_in, const int* in_sizes, int n_in,
                              void* d_out, int out_size, void* d_ws, size_t ws_size,
                              hipStream_t stream) {
    const float* ximg = (const float*)d_in[0];
    const float* xtxt = (const float*)d_in[1];
    const float* y    = (const float*)d_in[2];
    const float* Wimg = (const float*)d_in[3];
    const float* bimg = (const float*)d_in[4];
    const float* Wwrd = (const float*)d_in[5];
    const float* bwrd = (const float*)d_in[6];
    float* out = (float*)d_out;

    char* ws = (char*)d_ws;
    int*   idx  = (int*)(ws + OFF_IDX);
    float* part = (float*)(ws + OFF_PART);
    float* dotp = (float*)(ws + OFF_DOTP);
    float* ssqp = (float*)(ws + OFF_SSQP);
    u16*   WWb  = (u16*)(ws + OFF_WW);
    u16*   XTb  = (u16*)(ws + OFF_XT);

    const bool preconv = ws_size >= NEED_FULL;

    if (preconv) {
        k_conv_argmax<<<4097, 256, 0, stream>>>(Wwrd, WWb, ND * NE / 4,
                                                xtxt, XTb, MROWS * NE / 4, y, idx);
        k_gemm0<<<(ND / BN) * KSPLIT, 256, 0, stream>>>(ximg, idx, Wimg, part);
        k_gemm1<true, true><<<(MROWS / BM) * (ND / BN), 256, 0, stream>>>(
            XTb, WWb, bwrd, bimg, part, dotp, ssqp);
    } else {
        k_conv_argmax<<<1, 256, 0, stream>>>(nullptr, nullptr, 0,
                                             nullptr, nullptr, 0, y, idx);
        k_gemm0<<<(ND / BN) * KSPLIT, 256, 0, stream>>>(ximg, idx, Wimg, part);
        k_gemm1<false, false><<<(MROWS / BM) * (ND / BN), 256, 0, stream>>>(
            xtxt, Wwrd, bwrd, bimg, part, dotp, ssqp);
    }
    k_final<<<NB, 256, 0, stream>>>(part, bimg, dotp, ssqp, out);
}